// Round 1
// baseline (4794.310 us; speedup 1.0000x reference)
//
#include <hip/hip_runtime.h>
#include <math.h>

#define NN 100000
#define HID 128
#define EPSV 1e-5f

// ---------------- utility kernels ----------------

static __global__ void k_zero(float* __restrict__ p, int n) {
  int i = blockIdx.x * blockDim.x + threadIdx.x;
  if (i < n) p[i] = 0.f;
}

static __global__ void k_deg(const int* __restrict__ src, const int* __restrict__ dst,
                             int E, float* __restrict__ outdeg, float* __restrict__ indeg) {
  int e = blockIdx.x * blockDim.x + threadIdx.x;
  if (e < E) {
    atomicAdd(&outdeg[src[e]], 1.f);
    atomicAdd(&indeg[dst[e]], 1.f);
  }
}

static __global__ void k_rsqrt_clip(float* __restrict__ p, int n) {
  int i = blockIdx.x * blockDim.x + threadIdx.x;
  if (i < n) p[i] = rsqrtf(fmaxf(p[i], 1.f));
}

static __global__ void k_init_acc(float* __restrict__ acc, const float* __restrict__ b, int n) {
  int i = blockIdx.x * blockDim.x + threadIdx.x;
  if (i < n) {
    int j = i & 127;
    acc[i] = b[j] + b[128 + j] + b[256 + j];
  }
}

// ---------------- fused 3-relation GEMM with out-degree scaling ----------------
// Y[row, rel*128 + j] = sout[rel*NN + row] * sum_k A[row,k] * W[rel][k][j]
static __global__ __launch_bounds__(256)
void k_gemm_scaled(const float* __restrict__ A, int M, int K,
                   const float* __restrict__ W,      // [3][K][128]
                   const float* __restrict__ sout,   // [3][NN]
                   float* __restrict__ Y)            // [M][384]
{
  __shared__ float As[64][17];
  __shared__ float Bs[16][64];

  const int cb  = blockIdx.y;        // 0..5 (column block of 64)
  const int rel = cb >> 1;
  const int j0  = (cb & 1) * 64;
  const float* Wr = W + (size_t)rel * K * HID;
  const int row0 = blockIdx.x * 64;

  const int t    = threadIdx.x;
  const int arow = t >> 2;
  const int aq   = (t & 3) * 4;
  const int bk   = t >> 4;
  const int bq   = (t & 15) * 4;
  const int tx   = t & 15;
  const int ty   = t >> 4;

  float c[4][4];
#pragma unroll
  for (int i = 0; i < 4; ++i)
#pragma unroll
    for (int j = 0; j < 4; ++j) c[i][j] = 0.f;

  for (int k0 = 0; k0 < K; k0 += 16) {
    {
      int grow = row0 + arow;
      float4 v = make_float4(0.f, 0.f, 0.f, 0.f);
      if (grow < M) v = *(const float4*)&A[(size_t)grow * K + k0 + aq];
      As[arow][aq + 0] = v.x; As[arow][aq + 1] = v.y;
      As[arow][aq + 2] = v.z; As[arow][aq + 3] = v.w;
    }
    {
      float4 v = *(const float4*)&Wr[(size_t)(k0 + bk) * HID + j0 + bq];
      Bs[bk][bq + 0] = v.x; Bs[bk][bq + 1] = v.y;
      Bs[bk][bq + 2] = v.z; Bs[bk][bq + 3] = v.w;
    }
    __syncthreads();
#pragma unroll
    for (int kk = 0; kk < 16; ++kk) {
      float a0 = As[ty * 4 + 0][kk];
      float a1 = As[ty * 4 + 1][kk];
      float a2 = As[ty * 4 + 2][kk];
      float a3 = As[ty * 4 + 3][kk];
      float b0 = Bs[kk][tx * 4 + 0];
      float b1 = Bs[kk][tx * 4 + 1];
      float b2 = Bs[kk][tx * 4 + 2];
      float b3 = Bs[kk][tx * 4 + 3];
      c[0][0] = fmaf(a0, b0, c[0][0]); c[0][1] = fmaf(a0, b1, c[0][1]);
      c[0][2] = fmaf(a0, b2, c[0][2]); c[0][3] = fmaf(a0, b3, c[0][3]);
      c[1][0] = fmaf(a1, b0, c[1][0]); c[1][1] = fmaf(a1, b1, c[1][1]);
      c[1][2] = fmaf(a1, b2, c[1][2]); c[1][3] = fmaf(a1, b3, c[1][3]);
      c[2][0] = fmaf(a2, b0, c[2][0]); c[2][1] = fmaf(a2, b1, c[2][1]);
      c[2][2] = fmaf(a2, b2, c[2][2]); c[2][3] = fmaf(a2, b3, c[2][3]);
      c[3][0] = fmaf(a3, b0, c[3][0]); c[3][1] = fmaf(a3, b1, c[3][1]);
      c[3][2] = fmaf(a3, b2, c[3][2]); c[3][3] = fmaf(a3, b3, c[3][3]);
    }
    __syncthreads();
  }

#pragma unroll
  for (int i = 0; i < 4; ++i) {
    int grow = row0 + ty * 4 + i;
    if (grow < M) {
      float s = sout[(size_t)rel * NN + grow];
      float4 o = make_float4(c[i][0] * s, c[i][1] * s, c[i][2] * s, c[i][3] * s);
      *(float4*)&Y[(size_t)grow * 384 + cb * 64 + tx * 4] = o;
    }
  }
}

// ---------------- edge scatter: acc[dst] += indeg_scale[dst] * Y[src, rel block] ----------------
static __global__ __launch_bounds__(256)
void k_scatter(const int* __restrict__ src, const int* __restrict__ dst, int E,
               const float* __restrict__ sin_, const float* __restrict__ Y, int ycol0,
               float* __restrict__ acc)
{
  int e = blockIdx.x * 2 + (threadIdx.x >> 7);
  if (e >= E) return;
  int t = threadIdx.x & 127;
  int s = src[e];
  int d = dst[e];
  float w = sin_[d];
  float v = Y[(size_t)s * 384 + ycol0 + t] * w;
  atomicAdd(&acc[(size_t)d * HID + t], v);
}

// ---------------- FC (128x128) + bias + ReLU ----------------
// blockIdx.y in {0,1} selects a 64-wide column half; W half staged in LDS.
static __global__ __launch_bounds__(256)
void k_fc_relu(const float* __restrict__ X, int M,
               const float* __restrict__ Wfc, const float* __restrict__ bfc,
               float* __restrict__ Z)
{
  __shared__ float Ws[128 * 64];
  __shared__ float xs[4][128];
  const int j0 = blockIdx.y * 64;
  const int t = threadIdx.x;

  for (int i = t; i < 128 * 64; i += 256) {
    int k = i >> 6, c = i & 63;
    Ws[i] = Wfc[k * 128 + j0 + c];
  }
  const int rl = t >> 6;   // 0..3 : row lane within the 4-row group
  const int c  = t & 63;
  const float bb = bfc[j0 + c];
  __syncthreads();

  for (int row0 = blockIdx.x * 4; row0 < M; row0 += gridDim.x * 4) {
    int row = row0 + rl;
    if (row < M) {
      xs[rl][c]      = X[(size_t)row * 128 + c];
      xs[rl][c + 64] = X[(size_t)row * 128 + c + 64];
    }
    __syncthreads();
    if (row < M) {
      float acc = bb;
#pragma unroll
      for (int k = 0; k < 128; ++k)
        acc = fmaf(xs[rl][k], Ws[k * 64 + c], acc);
      Z[(size_t)row * 128 + j0 + c] = fmaxf(acc, 0.f);
    }
    __syncthreads();
  }
}

// ---------------- BatchNorm ----------------
static __global__ void k_bn_stats(const float* __restrict__ Z, int M, float* __restrict__ stats) {
  int col = threadIdx.x;  // 128 threads
  float s = 0.f, s2 = 0.f;
  for (int row = blockIdx.x; row < M; row += gridDim.x) {
    float v = Z[(size_t)row * 128 + col];
    s += v;
    s2 += v * v;
  }
  atomicAdd(&stats[col], s);
  atomicAdd(&stats[128 + col], s2);
}

static __global__ void k_bn_finalize(const float* __restrict__ stats, int M,
                                     const float* __restrict__ g, const float* __restrict__ beta,
                                     float* __restrict__ ab) {
  int j = threadIdx.x;  // 128
  float m  = stats[j] / (float)M;
  float v  = stats[128 + j] / (float)M - m * m;
  float inv = rsqrtf(v + EPSV) * g[j];
  ab[j]       = inv;
  ab[128 + j] = beta[j] - m * inv;
}

static __global__ void k_bn_apply(const float* __restrict__ Z, const float* __restrict__ ab,
                                  float* __restrict__ out, int n) {
  int i = blockIdx.x * blockDim.x + threadIdx.x;
  if (i < n) {
    int j = i & 127;
    out[i] = Z[i] * ab[j] + ab[128 + j];
  }
}

// ---------------- host-side layer driver ----------------

static void run_layer(const float* X, int K,
                      const float* W, const float* b,
                      const float* fcW, const float* fcb,
                      const float* g, const float* beta,
                      const int* const* srcs, const int* E,
                      float* sOut, float* sIn, float* Y, float* Z, float* acc,
                      float* stats, float* ab, float* out, hipStream_t stream)
{
  dim3 gg((NN + 63) / 64, 6);
  k_gemm_scaled<<<gg, 256, 0, stream>>>(X, NN, K, W, sOut, Y);

  k_init_acc<<<(NN * HID + 255) / 256, 256, 0, stream>>>(acc, b, NN * HID);

  for (int r = 0; r < 3; ++r) {
    k_scatter<<<(E[r] + 1) / 2, 256, 0, stream>>>(
        srcs[r], srcs[r] + E[r], E[r], sIn + (size_t)r * NN, Y, r * 128, acc);
  }

  k_fc_relu<<<dim3(2048, 2), 256, 0, stream>>>(acc, NN, fcW, fcb, Z);

  k_zero<<<1, 256, 0, stream>>>(stats, 256);
  k_bn_stats<<<1024, 128, 0, stream>>>(Z, NN, stats);
  k_bn_finalize<<<1, 128, 0, stream>>>(stats, NN, g, beta, ab);
  k_bn_apply<<<(NN * HID + 255) / 256, 256, 0, stream>>>(Z, ab, out, NN * HID);
}

extern "C" void kernel_launch(void* const* d_in, const int* in_sizes, int n_in,
                              void* d_out, int out_size, void* d_ws, size_t ws_size,
                              hipStream_t stream)
{
  const float* x    = (const float*)d_in[0];
  const int*   seq  = (const int*)d_in[1];
  const int*   knn  = (const int*)d_in[2];
  const int*   dis  = (const int*)d_in[3];
  const float* W0   = (const float*)d_in[4];
  const float* b0   = (const float*)d_in[5];
  const float* fcW0 = (const float*)d_in[6];
  const float* fcb0 = (const float*)d_in[7];
  const float* g0   = (const float*)d_in[8];
  const float* be0  = (const float*)d_in[9];
  const float* W1   = (const float*)d_in[10];
  const float* b1   = (const float*)d_in[11];
  const float* fcW1 = (const float*)d_in[12];
  const float* fcb1 = (const float*)d_in[13];
  const float* g1   = (const float*)d_in[14];
  const float* be1  = (const float*)d_in[15];

  const int E[3] = { in_sizes[1] / 2, in_sizes[2] / 2, in_sizes[3] / 2 };
  const int* srcs[3] = { seq, knn, dis };

  const size_t N = NN;
  float* ws    = (float*)d_ws;
  float* sOut  = ws;                    // 3N : per-relation outdeg^{-1/2}
  float* sIn   = sOut + 3 * N;          // 3N : per-relation indeg^{-1/2}
  float* Y     = sIn + 3 * N;           // N*384 projected features
  float* Z     = Y;                     // N*128 (aliases Y: Y dead after scatter)
  float* acc   = Y + N * 384;           // N*128 aggregated
  float* h     = acc + N * 128;         // N*128 layer-0 output
  float* stats = h + N * 128;           // 256
  float* ab    = stats + 256;           // 256

  // degrees (shared by both layers: same edge lists)
  k_zero<<<(6 * NN + 255) / 256, 256, 0, stream>>>(sOut, 6 * NN);
  for (int r = 0; r < 3; ++r) {
    k_deg<<<(E[r] + 255) / 256, 256, 0, stream>>>(
        srcs[r], srcs[r] + E[r], E[r], sOut + (size_t)r * N, sIn + (size_t)r * N);
  }
  k_rsqrt_clip<<<(6 * NN + 255) / 256, 256, 0, stream>>>(sOut, 6 * NN);

  // layer 0: x [N,1280] -> h [N,128]
  run_layer(x, 1280, W0, b0, fcW0, fcb0, g0, be0, srcs, E,
            sOut, sIn, Y, Z, acc, stats, ab, h, stream);

  // layer 1: h [N,128] -> d_out [N,128]
  run_layer(h, 128, W1, b1, fcW1, fcb1, g1, be1, srcs, E,
            sOut, sIn, Y, Z, acc, stats, ab, (float*)d_out, stream);
}

// Round 2
// 3592.194 us; speedup vs baseline: 1.3346x; 1.3346x over previous
//
#include <hip/hip_runtime.h>
#include <math.h>

#define NN 100000
#define HID 128
#define EPSV 1e-5f

typedef short bf16x8 __attribute__((ext_vector_type(8)));
typedef float f32x4 __attribute__((ext_vector_type(4)));
typedef unsigned short u16;

__device__ __forceinline__ u16 f2b(float f) {       // f32 -> bf16 RNE
  unsigned u = __builtin_bit_cast(unsigned, f);
  u += 0x7FFFu + ((u >> 16) & 1u);
  return (u16)(u >> 16);
}
__device__ __forceinline__ float b2f(u16 h) {
  unsigned u = ((unsigned)h) << 16;
  return __builtin_bit_cast(float, u);
}

#define AS1(p) ((__attribute__((address_space(1))) void*)(p))
#define AS3(p) ((__attribute__((address_space(3))) void*)(p))

// ---------------- utility kernels ----------------

static __global__ void k_zero(float* __restrict__ p, int n) {
  int i = blockIdx.x * blockDim.x + threadIdx.x;
  if (i < n) p[i] = 0.f;
}

static __global__ void k_deg(const int* __restrict__ src, const int* __restrict__ dst,
                             int E, float* __restrict__ outdeg, float* __restrict__ indeg) {
  int e = blockIdx.x * blockDim.x + threadIdx.x;
  if (e < E) {
    atomicAdd(&outdeg[src[e]], 1.f);
    atomicAdd(&indeg[dst[e]], 1.f);
  }
}

static __global__ void k_rsqrt_clip(float* __restrict__ p, int n) {
  int i = blockIdx.x * blockDim.x + threadIdx.x;
  if (i < n) p[i] = rsqrtf(fmaxf(p[i], 1.f));
}

static __global__ void k_init_acc(float* __restrict__ acc, const float* __restrict__ b, int n) {
  int i = blockIdx.x * blockDim.x + threadIdx.x;
  if (i < n) {
    int j = i & 127;
    acc[i] = b[j] + b[128 + j] + b[256 + j];
  }
}

// W [3][K][128] f32 -> Wt [3][128][K] bf16 (transposed so 8 consecutive k are contiguous)
static __global__ void k_cvt_w(const float* __restrict__ W, u16* __restrict__ Wt, int K) {
  int i = blockIdx.x * blockDim.x + threadIdx.x;
  int tot = 3 * K * 128;
  if (i < tot) {
    int rel = i / (K * 128);
    int rem = i - rel * K * 128;
    int k = rem >> 7;
    int c = rem & 127;
    Wt[((size_t)rel * 128 + c) * K + k] = f2b(W[i]);
  }
}

// ---------------- MFMA GEMM: Y[row, rel*128+j] = sout[rel][row] * (A[row,:] @ W_rel) ----------------
// BM=128, BN=128 (one relation per blockIdx.x), BK=32, 4 waves (2x2), each wave 64x64 = 4x4 frags.
// LDS is fragment-major: block m16 holds lane l's 16B at [m16*1024 + l*16] -> linear, conflict-free.
template<int K, bool ABF16>
__global__ __launch_bounds__(256)
void k_gemm_mfma(const void* __restrict__ Av,
                 const u16* __restrict__ Wt,    // [3][128][K] bf16
                 const float* __restrict__ sout,// [3][NN]
                 u16* __restrict__ Y,           // [M][384] bf16
                 int M)
{
  __shared__ u16 Al[4096];  // 8 KB
  __shared__ u16 Bl[4096];  // 8 KB

  const int rel  = blockIdx.x;     // 0..2 (fastest -> rel blocks of same row-tile co-resident)
  const int row0 = blockIdx.y * 128;
  const int t    = threadIdx.x;
  const int lane = t & 63;
  const int w    = t >> 6;         // wave 0..3
  const int wm   = w >> 1, wn = w & 1;
  const int l15  = lane & 15, l4 = lane >> 4;
  const int kl   = l4 * 8;

  const u16* Wr = Wt + (size_t)rel * 128 * K;

  int r0 = row0 + (2 * w) * 16 + l15;      if (r0 >= M) r0 = M - 1;  // clamp: dup reads, discarded on write
  int r1 = row0 + (2 * w + 1) * 16 + l15;  if (r1 >= M) r1 = M - 1;

  const u16* gb0 = Wr + (size_t)((2 * w) * 16 + l15) * K + kl;
  const u16* gb1 = Wr + (size_t)((2 * w + 1) * 16 + l15) * K + kl;
  u16* lA0 = &Al[(2 * w) * 512];
  u16* lA1 = &Al[(2 * w + 1) * 512];
  u16* lB0 = &Bl[(2 * w) * 512];
  u16* lB1 = &Bl[(2 * w + 1) * 512];

  const u16*   ga0 = nullptr; const u16*   ga1 = nullptr;
  const float* pa0 = nullptr; const float* pa1 = nullptr;
  if constexpr (ABF16) {
    const u16* A = (const u16*)Av;
    ga0 = A + (size_t)r0 * K + kl;
    ga1 = A + (size_t)r1 * K + kl;
  } else {
    const float* A = (const float*)Av;
    pa0 = A + (size_t)r0 * K + kl;
    pa1 = A + (size_t)r1 * K + kl;
  }

  f32x4 acc[4][4];
#pragma unroll
  for (int m = 0; m < 4; ++m)
#pragma unroll
    for (int n = 0; n < 4; ++n) acc[m][n] = (f32x4){0.f, 0.f, 0.f, 0.f};

  for (int k0 = 0; k0 < K; k0 += 32) {
    if constexpr (ABF16) {
      __builtin_amdgcn_global_load_lds(AS1(ga0 + k0), AS3(lA0), 16, 0, 0);
      __builtin_amdgcn_global_load_lds(AS1(ga1 + k0), AS3(lA1), 16, 0, 0);
    }
    __builtin_amdgcn_global_load_lds(AS1(gb0 + k0), AS3(lB0), 16, 0, 0);
    __builtin_amdgcn_global_load_lds(AS1(gb1 + k0), AS3(lB1), 16, 0, 0);
    if constexpr (!ABF16) {
      // reg-stage A from f32, cvt to bf16, fragment-major ds_write_b128
      float4 v0 = *(const float4*)(pa0 + k0);
      float4 v1 = *(const float4*)(pa0 + k0 + 4);
      float4 v2 = *(const float4*)(pa1 + k0);
      float4 v3 = *(const float4*)(pa1 + k0 + 4);
      union { bf16x8 v; u16 u[8]; } q0, q1;
      q0.u[0] = f2b(v0.x); q0.u[1] = f2b(v0.y); q0.u[2] = f2b(v0.z); q0.u[3] = f2b(v0.w);
      q0.u[4] = f2b(v1.x); q0.u[5] = f2b(v1.y); q0.u[6] = f2b(v1.z); q0.u[7] = f2b(v1.w);
      q1.u[0] = f2b(v2.x); q1.u[1] = f2b(v2.y); q1.u[2] = f2b(v2.z); q1.u[3] = f2b(v2.w);
      q1.u[4] = f2b(v3.x); q1.u[5] = f2b(v3.y); q1.u[6] = f2b(v3.z); q1.u[7] = f2b(v3.w);
      *(bf16x8*)&Al[(2 * w) * 512 + lane * 8] = q0.v;
      *(bf16x8*)&Al[(2 * w + 1) * 512 + lane * 8] = q1.v;
    }
    __syncthreads();
    bf16x8 a[4], b[4];
#pragma unroll
    for (int m = 0; m < 4; ++m) a[m] = *(const bf16x8*)&Al[(wm * 4 + m) * 512 + lane * 8];
#pragma unroll
    for (int n = 0; n < 4; ++n) b[n] = *(const bf16x8*)&Bl[(wn * 4 + n) * 512 + lane * 8];
#pragma unroll
    for (int m = 0; m < 4; ++m)
#pragma unroll
      for (int n = 0; n < 4; ++n)
        acc[m][n] = __builtin_amdgcn_mfma_f32_16x16x32_bf16(a[m], b[n], acc[m][n], 0, 0, 0);
    __syncthreads();
  }

  // epilogue: C layout col=lane&15, row=(lane>>4)*4+reg (m89-verified)
#pragma unroll
  for (int m = 0; m < 4; ++m) {
    const int rb = row0 + wm * 64 + m * 16 + l4 * 4;
#pragma unroll
    for (int j = 0; j < 4; ++j) {
      const int row = rb + j;
      if (row < M) {
        const float s = sout[(size_t)rel * NN + row];
        u16* yp = Y + (size_t)row * 384 + rel * 128 + wn * 64 + l15;
#pragma unroll
        for (int n = 0; n < 4; ++n) yp[n * 16] = f2b(acc[m][n][j] * s);
      }
    }
  }
}

// ---------------- edge scatter: acc[dst] += indeg_scale[dst] * Y_bf16[src, rel block] ----------------
static __global__ __launch_bounds__(256)
void k_scatter(const int* __restrict__ src, const int* __restrict__ dst, int E,
               const float* __restrict__ sin_, const u16* __restrict__ Y, int ycol0,
               float* __restrict__ acc)
{
  int e = blockIdx.x * 2 + (threadIdx.x >> 7);
  if (e >= E) return;
  int c = threadIdx.x & 127;
  int s = src[e];
  int d = dst[e];
  float wv = sin_[d];
  float v = b2f(Y[(size_t)s * 384 + ycol0 + c]) * wv;
  atomicAdd(&acc[(size_t)d * HID + c], v);
}

// ---------------- FC (128x128) + bias + ReLU ----------------
static __global__ __launch_bounds__(256)
void k_fc_relu(const float* __restrict__ X, int M,
               const float* __restrict__ Wfc, const float* __restrict__ bfc,
               float* __restrict__ Z)
{
  __shared__ float Ws[128 * 64];
  __shared__ float xs[4][128];
  const int j0 = blockIdx.y * 64;
  const int t = threadIdx.x;

  for (int i = t; i < 128 * 64; i += 256) {
    int k = i >> 6, c = i & 63;
    Ws[i] = Wfc[k * 128 + j0 + c];
  }
  const int rl = t >> 6;
  const int c  = t & 63;
  const float bb = bfc[j0 + c];
  __syncthreads();

  for (int row0 = blockIdx.x * 4; row0 < M; row0 += gridDim.x * 4) {
    int row = row0 + rl;
    if (row < M) {
      xs[rl][c]      = X[(size_t)row * 128 + c];
      xs[rl][c + 64] = X[(size_t)row * 128 + c + 64];
    }
    __syncthreads();
    if (row < M) {
      float acc = bb;
#pragma unroll
      for (int k = 0; k < 128; ++k)
        acc = fmaf(xs[rl][k], Ws[k * 64 + c], acc);
      Z[(size_t)row * 128 + j0 + c] = fmaxf(acc, 0.f);
    }
    __syncthreads();
  }
}

// ---------------- BatchNorm ----------------
static __global__ void k_bn_stats(const float* __restrict__ Z, int M, float* __restrict__ stats) {
  int col = threadIdx.x;  // 128 threads
  float s = 0.f, s2 = 0.f;
  for (int row = blockIdx.x; row < M; row += gridDim.x) {
    float v = Z[(size_t)row * 128 + col];
    s += v;
    s2 += v * v;
  }
  atomicAdd(&stats[col], s);
  atomicAdd(&stats[128 + col], s2);
}

static __global__ void k_bn_finalize(const float* __restrict__ stats, int M,
                                     const float* __restrict__ g, const float* __restrict__ beta,
                                     float* __restrict__ ab) {
  int j = threadIdx.x;  // 128
  float m  = stats[j] / (float)M;
  float v  = stats[128 + j] / (float)M - m * m;
  float inv = rsqrtf(v + EPSV) * g[j];
  ab[j]       = inv;
  ab[128 + j] = beta[j] - m * inv;
}

template<bool OUT_BF16>
static __global__ void k_bn_apply(const float* __restrict__ Z, const float* __restrict__ ab,
                                  void* __restrict__ out, int n) {
  int i = blockIdx.x * blockDim.x + threadIdx.x;
  if (i < n) {
    int j = i & 127;
    float v = Z[i] * ab[j] + ab[128 + j];
    if constexpr (OUT_BF16) ((u16*)out)[i] = f2b(v);
    else                    ((float*)out)[i] = v;
  }
}

// ---------------- host-side layer driver ----------------

template<int K, bool ABF16, bool OUT_BF16>
static void run_layer(const void* X,
                      const u16* Wt, const float* b,
                      const float* fcW, const float* fcb,
                      const float* g, const float* beta,
                      const int* const* srcs, const int* E,
                      float* sOut, float* sIn, u16* Y, float* Z, float* acc,
                      float* stats, float* ab, void* out, hipStream_t stream)
{
  k_gemm_mfma<K, ABF16><<<dim3(3, (NN + 127) / 128), 256, 0, stream>>>(X, Wt, sOut, Y, NN);

  k_init_acc<<<(NN * HID + 255) / 256, 256, 0, stream>>>(acc, b, NN * HID);

  for (int r = 0; r < 3; ++r) {
    k_scatter<<<(E[r] + 1) / 2, 256, 0, stream>>>(
        srcs[r], srcs[r] + E[r], E[r], sIn + (size_t)r * NN, Y, r * 128, acc);
  }

  k_fc_relu<<<dim3(2048, 2), 256, 0, stream>>>(acc, NN, fcW, fcb, Z);

  k_zero<<<1, 256, 0, stream>>>(stats, 256);
  k_bn_stats<<<1024, 128, 0, stream>>>(Z, NN, stats);
  k_bn_finalize<<<1, 128, 0, stream>>>(stats, NN, g, beta, ab);
  k_bn_apply<OUT_BF16><<<(NN * HID + 255) / 256, 256, 0, stream>>>(Z, ab, out, NN * HID);
}

extern "C" void kernel_launch(void* const* d_in, const int* in_sizes, int n_in,
                              void* d_out, int out_size, void* d_ws, size_t ws_size,
                              hipStream_t stream)
{
  const float* x    = (const float*)d_in[0];
  const int*   seq  = (const int*)d_in[1];
  const int*   knn  = (const int*)d_in[2];
  const int*   dis  = (const int*)d_in[3];
  const float* W0   = (const float*)d_in[4];
  const float* b0   = (const float*)d_in[5];
  const float* fcW0 = (const float*)d_in[6];
  const float* fcb0 = (const float*)d_in[7];
  const float* g0   = (const float*)d_in[8];
  const float* be0  = (const float*)d_in[9];
  const float* W1   = (const float*)d_in[10];
  const float* b1   = (const float*)d_in[11];
  const float* fcW1 = (const float*)d_in[12];
  const float* fcb1 = (const float*)d_in[13];
  const float* g1   = (const float*)d_in[14];
  const float* be1  = (const float*)d_in[15];

  const int E[3] = { in_sizes[1] / 2, in_sizes[2] / 2, in_sizes[3] / 2 };
  const int* srcs[3] = { seq, knn, dis };

  const size_t N = NN;
  float* ws    = (float*)d_ws;
  float* sOut  = ws;                        // 3N
  float* sIn   = sOut + 3 * N;              // 3N
  float* acc   = sIn + 3 * N;               // N*128
  float* stats = acc + N * 128;             // 256
  float* ab    = stats + 256;               // 256
  u16*   Y     = (u16*)(ab + 256);          // N*384 bf16 (aliased by Z below; Y dead after scatter)
  float* Z     = (float*)Y;                 // N*128 f32 (needs N*512B <= N*768B of Y region: OK)
  u16*   h16   = Y + N * 384;               // N*128 bf16 : layer-0 output
  u16*   Wt0   = h16 + N * 128;             // 3*128*1280 bf16
  u16*   Wt1   = Wt0 + 3 * 128 * 1280;      // 3*128*128 bf16
  // total ~157 MB, within the 258 MB proven in round 1

  // weight transpose+convert (tiny)
  k_cvt_w<<<(3 * 1280 * 128 + 255) / 256, 256, 0, stream>>>(W0, Wt0, 1280);
  k_cvt_w<<<(3 * 128 * 128 + 255) / 256, 256, 0, stream>>>(W1, Wt1, 128);

  // degrees (shared by both layers: same edge lists)
  k_zero<<<(6 * NN + 255) / 256, 256, 0, stream>>>(sOut, 6 * NN);
  for (int r = 0; r < 3; ++r) {
    k_deg<<<(E[r] + 255) / 256, 256, 0, stream>>>(
        srcs[r], srcs[r] + E[r], E[r], sOut + (size_t)r * N, sIn + (size_t)r * N);
  }
  k_rsqrt_clip<<<(6 * NN + 255) / 256, 256, 0, stream>>>(sOut, 6 * NN);

  // layer 0: x f32 [N,1280] -> h16 bf16 [N,128]
  run_layer<1280, false, true>(x, Wt0, b0, fcW0, fcb0, g0, be0, srcs, E,
                               sOut, sIn, Y, Z, acc, stats, ab, h16, stream);

  // layer 1: h16 bf16 [N,128] -> d_out f32 [N,128]
  run_layer<128, true, false>(h16, Wt1, b1, fcW1, fcb1, g1, be1, srcs, E,
                              sOut, sIn, Y, Z, acc, stats, ab, d_out, stream);
}

// Round 3
// 1870.851 us; speedup vs baseline: 2.5626x; 1.9201x over previous
//
#include <hip/hip_runtime.h>
#include <math.h>

#define NN 100000
#define HID 128
#define EPSV 1e-5f

typedef short bf16x8 __attribute__((ext_vector_type(8)));
typedef float f32x4 __attribute__((ext_vector_type(4)));
typedef unsigned short u16;

__device__ __forceinline__ u16 f2b(float f) {       // f32 -> bf16 RNE
  unsigned u = __builtin_bit_cast(unsigned, f);
  u += 0x7FFFu + ((u >> 16) & 1u);
  return (u16)(u >> 16);
}
__device__ __forceinline__ float b2f(u16 h) {
  unsigned u = ((unsigned)h) << 16;
  return __builtin_bit_cast(float, u);
}

#define AS1(p) ((__attribute__((address_space(1))) void*)(p))
#define AS3(p) ((__attribute__((address_space(3))) void*)(p))

// ---------------- utility kernels ----------------

static __global__ void k_zero(float* __restrict__ p, int n) {
  int i = blockIdx.x * blockDim.x + threadIdx.x;
  if (i < n) p[i] = 0.f;
}

static __global__ void k_zero_i(int* __restrict__ p, int n) {
  int i = blockIdx.x * blockDim.x + threadIdx.x;
  if (i < n) p[i] = 0;
}

static __global__ void k_deg(const int* __restrict__ src, const int* __restrict__ dst,
                             int E, float* __restrict__ outdeg, float* __restrict__ indeg) {
  int e = blockIdx.x * blockDim.x + threadIdx.x;
  if (e < E) {
    atomicAdd(&outdeg[src[e]], 1.f);
    atomicAdd(&indeg[dst[e]], 1.f);
  }
}

// counts[i] = (int)indeg_raw[i] for i<n3, counts[n3]=0  (before rsqrt_clip!)
static __global__ void k_counts(const float* __restrict__ indegRaw, int* __restrict__ counts, int n3) {
  int i = blockIdx.x * blockDim.x + threadIdx.x;
  if (i < n3) counts[i] = (int)indegRaw[i];
  else if (i == n3) counts[i] = 0;
}

static __global__ void k_rsqrt_clip(float* __restrict__ p, int n) {
  int i = blockIdx.x * blockDim.x + threadIdx.x;
  if (i < n) p[i] = rsqrtf(fmaxf(p[i], 1.f));
}

// ---------------- exclusive scan (two-level) ----------------
static __global__ void k_scan1(const int* __restrict__ in, int* __restrict__ out,
                               int* __restrict__ aux, int n) {
  __shared__ int s[256];
  int t = threadIdx.x, i = blockIdx.x * 256 + t;
  int v = (i < n) ? in[i] : 0;
  s[t] = v; __syncthreads();
#pragma unroll
  for (int d = 1; d < 256; d <<= 1) {
    int x = (t >= d) ? s[t - d] : 0;
    __syncthreads();
    s[t] += x;
    __syncthreads();
  }
  if (i < n) out[i] = s[t] - v;
  if (t == 255) aux[blockIdx.x] = s[255];
}

static __global__ void k_scan2(int* __restrict__ aux, int nb) {
  __shared__ int s[256];
  __shared__ int carry;
  int t = threadIdx.x;
  if (t == 0) carry = 0;
  __syncthreads();
  for (int base = 0; base < nb; base += 256) {
    int i = base + t;
    int v = (i < nb) ? aux[i] : 0;
    s[t] = v; __syncthreads();
#pragma unroll
    for (int d = 1; d < 256; d <<= 1) {
      int x = (t >= d) ? s[t - d] : 0;
      __syncthreads();
      s[t] += x;
      __syncthreads();
    }
    int excl = s[t] - v + carry;
    if (i < nb) aux[i] = excl;
    int tot = s[255];
    __syncthreads();
    if (t == 0) carry += tot;
    __syncthreads();
  }
}

static __global__ void k_scan3(int* __restrict__ out, const int* __restrict__ aux, int n) {
  int i = blockIdx.x * 256 + threadIdx.x;
  if (i < n) out[i] += aux[blockIdx.x];
}

// fill CSR buckets: srt[off[rbase+dst] + cursor++] = src
static __global__ void k_fill(const int* __restrict__ src, const int* __restrict__ dst, int E,
                              const int* __restrict__ off, int* __restrict__ cur,
                              int rbase, int* __restrict__ srt) {
  int e = blockIdx.x * blockDim.x + threadIdx.x;
  if (e < E) {
    int d = dst[e];
    int p = off[rbase + d] + atomicAdd(&cur[rbase + d], 1);
    srt[p] = src[e];
  }
}

// W [3][K][128] f32 -> Wt [3][128][K] bf16 (transposed so 8 consecutive k are contiguous)
static __global__ void k_cvt_w(const float* __restrict__ W, u16* __restrict__ Wt, int K) {
  int i = blockIdx.x * blockDim.x + threadIdx.x;
  int tot = 3 * K * 128;
  if (i < tot) {
    int rel = i / (K * 128);
    int rem = i - rel * K * 128;
    int k = rem >> 7;
    int c = rem & 127;
    Wt[((size_t)rel * 128 + c) * K + k] = f2b(W[i]);
  }
}

// ---------------- MFMA GEMM: Y[row, rel*128+j] = sout[rel][row] * (A[row,:] @ W_rel) ----------------
template<int K, bool ABF16>
__global__ __launch_bounds__(256)
void k_gemm_mfma(const void* __restrict__ Av,
                 const u16* __restrict__ Wt,    // [3][128][K] bf16
                 const float* __restrict__ sout,// [3][NN]
                 u16* __restrict__ Y,           // [M][384] bf16
                 int M)
{
  __shared__ u16 Al[4096];  // 8 KB
  __shared__ u16 Bl[4096];  // 8 KB

  const int rel  = blockIdx.x;     // 0..2
  const int row0 = blockIdx.y * 128;
  const int t    = threadIdx.x;
  const int lane = t & 63;
  const int w    = t >> 6;
  const int wm   = w >> 1, wn = w & 1;
  const int l15  = lane & 15, l4 = lane >> 4;
  const int kl   = l4 * 8;

  const u16* Wr = Wt + (size_t)rel * 128 * K;

  int r0 = row0 + (2 * w) * 16 + l15;      if (r0 >= M) r0 = M - 1;
  int r1 = row0 + (2 * w + 1) * 16 + l15;  if (r1 >= M) r1 = M - 1;

  const u16* gb0 = Wr + (size_t)((2 * w) * 16 + l15) * K + kl;
  const u16* gb1 = Wr + (size_t)((2 * w + 1) * 16 + l15) * K + kl;
  u16* lA0 = &Al[(2 * w) * 512];
  u16* lA1 = &Al[(2 * w + 1) * 512];
  u16* lB0 = &Bl[(2 * w) * 512];
  u16* lB1 = &Bl[(2 * w + 1) * 512];

  const u16*   ga0 = nullptr; const u16*   ga1 = nullptr;
  const float* pa0 = nullptr; const float* pa1 = nullptr;
  if constexpr (ABF16) {
    const u16* A = (const u16*)Av;
    ga0 = A + (size_t)r0 * K + kl;
    ga1 = A + (size_t)r1 * K + kl;
  } else {
    const float* A = (const float*)Av;
    pa0 = A + (size_t)r0 * K + kl;
    pa1 = A + (size_t)r1 * K + kl;
  }

  f32x4 acc[4][4];
#pragma unroll
  for (int m = 0; m < 4; ++m)
#pragma unroll
    for (int n = 0; n < 4; ++n) acc[m][n] = (f32x4){0.f, 0.f, 0.f, 0.f};

  for (int k0 = 0; k0 < K; k0 += 32) {
    if constexpr (ABF16) {
      __builtin_amdgcn_global_load_lds(AS1(ga0 + k0), AS3(lA0), 16, 0, 0);
      __builtin_amdgcn_global_load_lds(AS1(ga1 + k0), AS3(lA1), 16, 0, 0);
    }
    __builtin_amdgcn_global_load_lds(AS1(gb0 + k0), AS3(lB0), 16, 0, 0);
    __builtin_amdgcn_global_load_lds(AS1(gb1 + k0), AS3(lB1), 16, 0, 0);
    if constexpr (!ABF16) {
      float4 v0 = *(const float4*)(pa0 + k0);
      float4 v1 = *(const float4*)(pa0 + k0 + 4);
      float4 v2 = *(const float4*)(pa1 + k0);
      float4 v3 = *(const float4*)(pa1 + k0 + 4);
      union { bf16x8 v; u16 u[8]; } q0, q1;
      q0.u[0] = f2b(v0.x); q0.u[1] = f2b(v0.y); q0.u[2] = f2b(v0.z); q0.u[3] = f2b(v0.w);
      q0.u[4] = f2b(v1.x); q0.u[5] = f2b(v1.y); q0.u[6] = f2b(v1.z); q0.u[7] = f2b(v1.w);
      q1.u[0] = f2b(v2.x); q1.u[1] = f2b(v2.y); q1.u[2] = f2b(v2.z); q1.u[3] = f2b(v2.w);
      q1.u[4] = f2b(v3.x); q1.u[5] = f2b(v3.y); q1.u[6] = f2b(v3.z); q1.u[7] = f2b(v3.w);
      *(bf16x8*)&Al[(2 * w) * 512 + lane * 8] = q0.v;
      *(bf16x8*)&Al[(2 * w + 1) * 512 + lane * 8] = q1.v;
    }
    __syncthreads();
    bf16x8 a[4], b[4];
#pragma unroll
    for (int m = 0; m < 4; ++m) a[m] = *(const bf16x8*)&Al[(wm * 4 + m) * 512 + lane * 8];
#pragma unroll
    for (int n = 0; n < 4; ++n) b[n] = *(const bf16x8*)&Bl[(wn * 4 + n) * 512 + lane * 8];
#pragma unroll
    for (int m = 0; m < 4; ++m)
#pragma unroll
      for (int n = 0; n < 4; ++n)
        acc[m][n] = __builtin_amdgcn_mfma_f32_16x16x32_bf16(a[m], b[n], acc[m][n], 0, 0, 0);
    __syncthreads();
  }

#pragma unroll
  for (int m = 0; m < 4; ++m) {
    const int rb = row0 + wm * 64 + m * 16 + l4 * 4;
#pragma unroll
    for (int j = 0; j < 4; ++j) {
      const int row = rb + j;
      if (row < M) {
        const float s = sout[(size_t)rel * NN + row];
        u16* yp = Y + (size_t)row * 384 + rel * 128 + wn * 64 + l15;
#pragma unroll
        for (int n = 0; n < 4; ++n) yp[n * 16] = f2b(acc[m][n][j] * s);
      }
    }
  }
}

// ---------------- CSR gather: acc[d,:] = sum_r sin[r][d] * sum_{e in bucket(r,d)} Y[src_e, r] + bias ----------------
// one wave per node; lane handles cols {2l, 2l+1} via a single u32 load per edge.
static __global__ __launch_bounds__(256)
void k_gather(const int* __restrict__ off, const int* __restrict__ srt,
              const float* __restrict__ sin_, const u16* __restrict__ Y,
              const float* __restrict__ b, float* __restrict__ acc)
{
  int d = blockIdx.x * 4 + (threadIdx.x >> 6);
  if (d >= NN) return;
  int c = (threadIdx.x & 63) * 2;
  float v0 = b[c]     + b[128 + c]     + b[256 + c];
  float v1 = b[c + 1] + b[128 + c + 1] + b[256 + c + 1];
#pragma unroll
  for (int r = 0; r < 3; ++r) {
    int base = r * NN + d;
    int j0 = off[base], j1 = off[base + 1];
    float p0 = 0.f, p1 = 0.f;
    for (int j = j0; j < j1; ++j) {
      int s = srt[j];
      unsigned u = *(const unsigned*)&Y[(size_t)s * 384 + r * 128 + c];
      p0 += b2f((u16)(u & 0xFFFFu));
      p1 += b2f((u16)(u >> 16));
    }
    float sc = sin_[base];
    v0 += p0 * sc;
    v1 += p1 * sc;
  }
  *(float2*)&acc[(size_t)d * 128 + c] = make_float2(v0, v1);
}

// ---------------- FC (128x128) + bias + ReLU ----------------
static __global__ __launch_bounds__(256)
void k_fc_relu(const float* __restrict__ X, int M,
               const float* __restrict__ Wfc, const float* __restrict__ bfc,
               float* __restrict__ Z)
{
  __shared__ float Ws[128 * 64];
  __shared__ float xs[4][128];
  const int j0 = blockIdx.y * 64;
  const int t = threadIdx.x;

  for (int i = t; i < 128 * 64; i += 256) {
    int k = i >> 6, c = i & 63;
    Ws[i] = Wfc[k * 128 + j0 + c];
  }
  const int rl = t >> 6;
  const int c  = t & 63;
  const float bb = bfc[j0 + c];
  __syncthreads();

  for (int row0 = blockIdx.x * 4; row0 < M; row0 += gridDim.x * 4) {
    int row = row0 + rl;
    if (row < M) {
      xs[rl][c]      = X[(size_t)row * 128 + c];
      xs[rl][c + 64] = X[(size_t)row * 128 + c + 64];
    }
    __syncthreads();
    if (row < M) {
      float acc = bb;
#pragma unroll
      for (int k = 0; k < 128; ++k)
        acc = fmaf(xs[rl][k], Ws[k * 64 + c], acc);
      Z[(size_t)row * 128 + j0 + c] = fmaxf(acc, 0.f);
    }
    __syncthreads();
  }
}

// ---------------- BatchNorm ----------------
static __global__ void k_bn_stats(const float* __restrict__ Z, int M, float* __restrict__ stats) {
  int col = threadIdx.x;  // 128
  float s = 0.f, s2 = 0.f;
  for (int row = blockIdx.x; row < M; row += gridDim.x) {
    float v = Z[(size_t)row * 128 + col];
    s += v;
    s2 += v * v;
  }
  atomicAdd(&stats[col], s);
  atomicAdd(&stats[128 + col], s2);
}

static __global__ void k_bn_finalize(const float* __restrict__ stats, int M,
                                     const float* __restrict__ g, const float* __restrict__ beta,
                                     float* __restrict__ ab) {
  int j = threadIdx.x;  // 128
  float m  = stats[j] / (float)M;
  float v  = stats[128 + j] / (float)M - m * m;
  float inv = rsqrtf(v + EPSV) * g[j];
  ab[j]       = inv;
  ab[128 + j] = beta[j] - m * inv;
}

template<bool OUT_BF16>
static __global__ void k_bn_apply(const float* __restrict__ Z, const float* __restrict__ ab,
                                  void* __restrict__ out, int n) {
  int i = blockIdx.x * blockDim.x + threadIdx.x;
  if (i < n) {
    int j = i & 127;
    float v = Z[i] * ab[j] + ab[128 + j];
    if constexpr (OUT_BF16) ((u16*)out)[i] = f2b(v);
    else                    ((float*)out)[i] = v;
  }
}

// ---------------- host-side layer driver ----------------

template<int K, bool ABF16, bool OUT_BF16>
static void run_layer(const void* X,
                      const u16* Wt, const float* b,
                      const float* fcW, const float* fcb,
                      const float* g, const float* beta,
                      const int* off, const int* srt,
                      float* sOut, float* sIn, u16* Y, float* Z, float* acc,
                      float* stats, float* ab, void* out, hipStream_t stream)
{
  k_gemm_mfma<K, ABF16><<<dim3(3, (NN + 127) / 128), 256, 0, stream>>>(X, Wt, sOut, Y, NN);

  k_gather<<<(NN + 3) / 4, 256, 0, stream>>>(off, srt, sIn, Y, b, acc);

  k_fc_relu<<<dim3(2048, 2), 256, 0, stream>>>(acc, NN, fcW, fcb, Z);

  k_zero<<<1, 256, 0, stream>>>(stats, 256);
  k_bn_stats<<<1024, 128, 0, stream>>>(Z, NN, stats);
  k_bn_finalize<<<1, 128, 0, stream>>>(stats, NN, g, beta, ab);
  k_bn_apply<OUT_BF16><<<(NN * HID + 255) / 256, 256, 0, stream>>>(Z, ab, out, NN * HID);
}

extern "C" void kernel_launch(void* const* d_in, const int* in_sizes, int n_in,
                              void* d_out, int out_size, void* d_ws, size_t ws_size,
                              hipStream_t stream)
{
  const float* x    = (const float*)d_in[0];
  const int*   seq  = (const int*)d_in[1];
  const int*   knn  = (const int*)d_in[2];
  const int*   dis  = (const int*)d_in[3];
  const float* W0   = (const float*)d_in[4];
  const float* b0   = (const float*)d_in[5];
  const float* fcW0 = (const float*)d_in[6];
  const float* fcb0 = (const float*)d_in[7];
  const float* g0   = (const float*)d_in[8];
  const float* be0  = (const float*)d_in[9];
  const float* W1   = (const float*)d_in[10];
  const float* b1   = (const float*)d_in[11];
  const float* fcW1 = (const float*)d_in[12];
  const float* fcb1 = (const float*)d_in[13];
  const float* g1   = (const float*)d_in[14];
  const float* be1  = (const float*)d_in[15];

  const int E[3] = { in_sizes[1] / 2, in_sizes[2] / 2, in_sizes[3] / 2 };
  const int* srcs[3] = { seq, knn, dis };
  const int ETOT = E[0] + E[1] + E[2];

  const size_t N = NN;
  const int M3 = 3 * NN;

  float* ws    = (float*)d_ws;
  float* sOut  = ws;                        // 3N
  float* sIn   = sOut + 3 * N;              // 3N
  float* acc   = sIn + 3 * N;               // N*128
  float* stats = acc + N * 128;             // 256
  float* ab    = stats + 256;               // 256
  u16*   Y     = (u16*)(ab + 256);          // N*384 bf16 (Z aliases: Y dead after gather)
  float* Z     = (float*)Y;                 // N*128 f32
  u16*   h16   = Y + N * 384;               // N*128 bf16
  u16*   Wt0   = h16 + N * 128;             // 3*128*1280
  u16*   Wt1   = Wt0 + 3 * 128 * 1280;      // 3*128*128
  int*   counts= (int*)(Wt1 + 3 * 128 * 128);
  int*   off   = counts + (M3 + 1);
  int*   aux   = off + (M3 + 1);
  int*   cur   = aux + 1536;
  int*   srt   = cur + M3;                  // ETOT ints
  // total ~172 MB

  // weight transpose+convert
  k_cvt_w<<<(3 * 1280 * 128 + 255) / 256, 256, 0, stream>>>(W0, Wt0, 1280);
  k_cvt_w<<<(3 * 128 * 128 + 255) / 256, 256, 0, stream>>>(W1, Wt1, 128);

  // degrees
  k_zero<<<(6 * NN + 255) / 256, 256, 0, stream>>>(sOut, 6 * NN);
  for (int r = 0; r < 3; ++r) {
    k_deg<<<(E[r] + 255) / 256, 256, 0, stream>>>(
        srcs[r], srcs[r] + E[r], E[r], sOut + (size_t)r * N, sIn + (size_t)r * N);
  }
  // int counts from raw in-degrees (before clip)
  k_counts<<<(M3 + 1 + 255) / 256, 256, 0, stream>>>(sIn, counts, M3);
  k_rsqrt_clip<<<(6 * NN + 255) / 256, 256, 0, stream>>>(sOut, 6 * NN);

  // CSR: exclusive scan of counts[M3+1] -> off (off[M3] = ETOT)
  const int nsc = M3 + 1;
  const int nb  = (nsc + 255) / 256;
  k_scan1<<<nb, 256, 0, stream>>>(counts, off, aux, nsc);
  k_scan2<<<1, 256, 0, stream>>>(aux, nb);
  k_scan3<<<nb, 256, 0, stream>>>(off, aux, nsc);

  k_zero_i<<<(M3 + 255) / 256, 256, 0, stream>>>(cur, M3);
  for (int r = 0; r < 3; ++r) {
    k_fill<<<(E[r] + 255) / 256, 256, 0, stream>>>(
        srcs[r], srcs[r] + E[r], E[r], off, cur, r * NN, srt);
  }

  // layer 0: x f32 [N,1280] -> h16 bf16 [N,128]
  run_layer<1280, false, true>(x, Wt0, b0, fcW0, fcb0, g0, be0, off, srt,
                               sOut, sIn, Y, Z, acc, stats, ab, h16, stream);

  // layer 1: h16 bf16 [N,128] -> d_out f32 [N,128]
  run_layer<128, true, false>(h16, Wt1, b1, fcW1, fcb1, g1, be1, off, srt,
                              sOut, sIn, Y, Z, acc, stats, ab, d_out, stream);
}

// Round 4
// 1847.752 us; speedup vs baseline: 2.5947x; 1.0125x over previous
//
#include <hip/hip_runtime.h>
#include <math.h>

#define NN 100000
#define HID 128
#define EPSV 1e-5f

typedef short bf16x8 __attribute__((ext_vector_type(8)));
typedef float f32x4 __attribute__((ext_vector_type(4)));
typedef unsigned short u16;

__device__ __forceinline__ u16 f2b(float f) {       // f32 -> bf16 RNE
  unsigned u = __builtin_bit_cast(unsigned, f);
  u += 0x7FFFu + ((u >> 16) & 1u);
  return (u16)(u >> 16);
}
__device__ __forceinline__ float b2f(u16 h) {
  unsigned u = ((unsigned)h) << 16;
  return __builtin_bit_cast(float, u);
}

#define AS1(p) ((__attribute__((address_space(1))) void*)(p))
#define AS3(p) ((__attribute__((address_space(3))) void*)(p))

// ---------------- utility kernels ----------------

static __global__ void k_zero(float* __restrict__ p, int n) {
  int i = blockIdx.x * blockDim.x + threadIdx.x;
  if (i < n) p[i] = 0.f;
}

static __global__ void k_zero_i(int* __restrict__ p, int n) {
  int i = blockIdx.x * blockDim.x + threadIdx.x;
  if (i < n) p[i] = 0;
}

static __global__ void k_deg(const int* __restrict__ src, const int* __restrict__ dst,
                             int E, float* __restrict__ outdeg, float* __restrict__ indeg) {
  int e = blockIdx.x * blockDim.x + threadIdx.x;
  if (e < E) {
    atomicAdd(&outdeg[src[e]], 1.f);
    atomicAdd(&indeg[dst[e]], 1.f);
  }
}

static __global__ void k_counts(const float* __restrict__ indegRaw, int* __restrict__ counts, int n3) {
  int i = blockIdx.x * blockDim.x + threadIdx.x;
  if (i < n3) counts[i] = (int)indegRaw[i];
  else if (i == n3) counts[i] = 0;
}

static __global__ void k_rsqrt_clip(float* __restrict__ p, int n) {
  int i = blockIdx.x * blockDim.x + threadIdx.x;
  if (i < n) p[i] = rsqrtf(fmaxf(p[i], 1.f));
}

// ---------------- exclusive scan (two-level) ----------------
static __global__ void k_scan1(const int* __restrict__ in, int* __restrict__ out,
                               int* __restrict__ aux, int n) {
  __shared__ int s[256];
  int t = threadIdx.x, i = blockIdx.x * 256 + t;
  int v = (i < n) ? in[i] : 0;
  s[t] = v; __syncthreads();
#pragma unroll
  for (int d = 1; d < 256; d <<= 1) {
    int x = (t >= d) ? s[t - d] : 0;
    __syncthreads();
    s[t] += x;
    __syncthreads();
  }
  if (i < n) out[i] = s[t] - v;
  if (t == 255) aux[blockIdx.x] = s[255];
}

static __global__ void k_scan2(int* __restrict__ aux, int nb) {
  __shared__ int s[256];
  __shared__ int carry;
  int t = threadIdx.x;
  if (t == 0) carry = 0;
  __syncthreads();
  for (int base = 0; base < nb; base += 256) {
    int i = base + t;
    int v = (i < nb) ? aux[i] : 0;
    s[t] = v; __syncthreads();
#pragma unroll
    for (int d = 1; d < 256; d <<= 1) {
      int x = (t >= d) ? s[t - d] : 0;
      __syncthreads();
      s[t] += x;
      __syncthreads();
    }
    int excl = s[t] - v + carry;
    if (i < nb) aux[i] = excl;
    int tot = s[255];
    __syncthreads();
    if (t == 0) carry += tot;
    __syncthreads();
  }
}

static __global__ void k_scan3(int* __restrict__ out, const int* __restrict__ aux, int n) {
  int i = blockIdx.x * 256 + threadIdx.x;
  if (i < n) out[i] += aux[blockIdx.x];
}

static __global__ void k_fill(const int* __restrict__ src, const int* __restrict__ dst, int E,
                              const int* __restrict__ off, int* __restrict__ cur,
                              int rbase, int* __restrict__ srt) {
  int e = blockIdx.x * blockDim.x + threadIdx.x;
  if (e < E) {
    int d = dst[e];
    int p = off[rbase + d] + atomicAdd(&cur[rbase + d], 1);
    srt[p] = src[e];
  }
}

// W [3][K][128] f32 -> Wt [3][128][K] bf16
static __global__ void k_cvt_w(const float* __restrict__ W, u16* __restrict__ Wt, int K) {
  int i = blockIdx.x * blockDim.x + threadIdx.x;
  int tot = 3 * K * 128;
  if (i < tot) {
    int rel = i / (K * 128);
    int rem = i - rel * K * 128;
    int k = rem >> 7;
    int c = rem & 127;
    Wt[((size_t)rel * 128 + c) * K + k] = f2b(W[i]);
  }
}

// ---------------- MFMA GEMM: Y[row, rel*128+j] = sout[rel][row] * (A[row,:] @ W_rel) ----------------
// XCD-swizzled 1D grid: the 3 rel-blocks of one row-tile land on the same XCD (L2 A-sharing).
// Double-buffered LDS; next-step A (f32 regs) / B (global_load_lds) issued before the MFMA cluster.
template<int K, bool ABF16>
__global__ __launch_bounds__(256)
void k_gemm_mfma(const void* __restrict__ Av,
                 const u16* __restrict__ Wt,    // [3][128][K] bf16
                 const float* __restrict__ sout,// [3][NN]
                 u16* __restrict__ Y,           // [M][384] bf16
                 int M, int NT)
{
  __shared__ u16 Al[2][4096];  // 2 x 8 KB
  __shared__ u16 Bl[2][4096];

  const int bid  = blockIdx.x;
  const int xcd  = bid & 7;
  const int s    = bid >> 3;
  const int rel  = s % 3;
  const int tile = xcd + 8 * (s / 3);
  if (tile >= NT) return;
  const int row0 = tile * 128;

  const int t    = threadIdx.x;
  const int lane = t & 63;
  const int w    = t >> 6;
  const int wm   = w >> 1, wn = w & 1;
  const int l15  = lane & 15, l4 = lane >> 4;
  const int kl   = l4 * 8;
  const int nk   = K / 32;

  const u16* Wr = Wt + (size_t)rel * 128 * K;

  int r0 = row0 + (2 * w) * 16 + l15;      if (r0 >= M) r0 = M - 1;
  int r1 = row0 + (2 * w + 1) * 16 + l15;  if (r1 >= M) r1 = M - 1;

  const u16* gb0 = Wr + (size_t)((2 * w) * 16 + l15) * K + kl;
  const u16* gb1 = Wr + (size_t)((2 * w + 1) * 16 + l15) * K + kl;

  const u16*   ga0 = nullptr; const u16*   ga1 = nullptr;
  const float* pa0 = nullptr; const float* pa1 = nullptr;
  if constexpr (ABF16) {
    const u16* A = (const u16*)Av;
    ga0 = A + (size_t)r0 * K + kl;
    ga1 = A + (size_t)r1 * K + kl;
  } else {
    const float* A = (const float*)Av;
    pa0 = A + (size_t)r0 * K + kl;
    pa1 = A + (size_t)r1 * K + kl;
  }

  f32x4 acc[4][4];
#pragma unroll
  for (int m = 0; m < 4; ++m)
#pragma unroll
    for (int n = 0; n < 4; ++n) acc[m][n] = (f32x4){0.f, 0.f, 0.f, 0.f};

  // ---- prologue: stage k=0 into buffer 0 ----
  __builtin_amdgcn_global_load_lds(AS1(gb0), AS3(&Bl[0][(2 * w) * 512]), 16, 0, 0);
  __builtin_amdgcn_global_load_lds(AS1(gb1), AS3(&Bl[0][(2 * w + 1) * 512]), 16, 0, 0);
  if constexpr (ABF16) {
    __builtin_amdgcn_global_load_lds(AS1(ga0), AS3(&Al[0][(2 * w) * 512]), 16, 0, 0);
    __builtin_amdgcn_global_load_lds(AS1(ga1), AS3(&Al[0][(2 * w + 1) * 512]), 16, 0, 0);
  } else {
    float4 v0 = *(const float4*)(pa0);
    float4 v1 = *(const float4*)(pa0 + 4);
    float4 v2 = *(const float4*)(pa1);
    float4 v3 = *(const float4*)(pa1 + 4);
    union { bf16x8 v; u16 u[8]; } q0, q1;
    q0.u[0] = f2b(v0.x); q0.u[1] = f2b(v0.y); q0.u[2] = f2b(v0.z); q0.u[3] = f2b(v0.w);
    q0.u[4] = f2b(v1.x); q0.u[5] = f2b(v1.y); q0.u[6] = f2b(v1.z); q0.u[7] = f2b(v1.w);
    q1.u[0] = f2b(v2.x); q1.u[1] = f2b(v2.y); q1.u[2] = f2b(v2.z); q1.u[3] = f2b(v2.w);
    q1.u[4] = f2b(v3.x); q1.u[5] = f2b(v3.y); q1.u[6] = f2b(v3.z); q1.u[7] = f2b(v3.w);
    *(bf16x8*)&Al[0][(2 * w) * 512 + lane * 8] = q0.v;
    *(bf16x8*)&Al[0][(2 * w + 1) * 512 + lane * 8] = q1.v;
  }
  __syncthreads();

#pragma unroll 2
  for (int k = 0; k < nk; ++k) {
    const int cur = k & 1, nxt = cur ^ 1;
    const int k1 = (k + 1) * 32;

    // fragments for this step
    bf16x8 a[4], b[4];
#pragma unroll
    for (int m = 0; m < 4; ++m) a[m] = *(const bf16x8*)&Al[cur][(wm * 4 + m) * 512 + lane * 8];
#pragma unroll
    for (int n = 0; n < 4; ++n) b[n] = *(const bf16x8*)&Bl[cur][(wn * 4 + n) * 512 + lane * 8];

    // issue next-step loads early (latency hidden under MFMA cluster)
    float4 v0, v1, v2, v3;
    if (k + 1 < nk) {
      __builtin_amdgcn_global_load_lds(AS1(gb0 + k1), AS3(&Bl[nxt][(2 * w) * 512]), 16, 0, 0);
      __builtin_amdgcn_global_load_lds(AS1(gb1 + k1), AS3(&Bl[nxt][(2 * w + 1) * 512]), 16, 0, 0);
      if constexpr (ABF16) {
        __builtin_amdgcn_global_load_lds(AS1(ga0 + k1), AS3(&Al[nxt][(2 * w) * 512]), 16, 0, 0);
        __builtin_amdgcn_global_load_lds(AS1(ga1 + k1), AS3(&Al[nxt][(2 * w + 1) * 512]), 16, 0, 0);
      } else {
        v0 = *(const float4*)(pa0 + k1);
        v1 = *(const float4*)(pa0 + k1 + 4);
        v2 = *(const float4*)(pa1 + k1);
        v3 = *(const float4*)(pa1 + k1 + 4);
      }
    }

#pragma unroll
    for (int m = 0; m < 4; ++m)
#pragma unroll
      for (int n = 0; n < 4; ++n)
        acc[m][n] = __builtin_amdgcn_mfma_f32_16x16x32_bf16(a[m], b[n], acc[m][n], 0, 0, 0);

    if constexpr (!ABF16) {
      if (k + 1 < nk) {
        union { bf16x8 v; u16 u[8]; } q0, q1;
        q0.u[0] = f2b(v0.x); q0.u[1] = f2b(v0.y); q0.u[2] = f2b(v0.z); q0.u[3] = f2b(v0.w);
        q0.u[4] = f2b(v1.x); q0.u[5] = f2b(v1.y); q0.u[6] = f2b(v1.z); q0.u[7] = f2b(v1.w);
        q1.u[0] = f2b(v2.x); q1.u[1] = f2b(v2.y); q1.u[2] = f2b(v2.z); q1.u[3] = f2b(v2.w);
        q1.u[4] = f2b(v3.x); q1.u[5] = f2b(v3.y); q1.u[6] = f2b(v3.z); q1.u[7] = f2b(v3.w);
        *(bf16x8*)&Al[nxt][(2 * w) * 512 + lane * 8] = q0.v;
        *(bf16x8*)&Al[nxt][(2 * w + 1) * 512 + lane * 8] = q1.v;
      }
    }
    __syncthreads();
  }

  // epilogue: C layout col=lane&15, row=(lane>>4)*4+reg
#pragma unroll
  for (int m = 0; m < 4; ++m) {
    const int rb = row0 + wm * 64 + m * 16 + l4 * 4;
#pragma unroll
    for (int j = 0; j < 4; ++j) {
      const int row = rb + j;
      if (row < M) {
        const float sc = sout[(size_t)rel * NN + row];
        u16* yp = Y + (size_t)row * 384 + rel * 128 + wn * 64 + l15;
#pragma unroll
        for (int n = 0; n < 4; ++n) yp[n * 16] = f2b(acc[m][n][j] * sc);
      }
    }
  }
}

// ---------------- CSR gather ----------------
static __global__ __launch_bounds__(256)
void k_gather(const int* __restrict__ off, const int* __restrict__ srt,
              const float* __restrict__ sin_, const u16* __restrict__ Y,
              const float* __restrict__ b, float* __restrict__ acc)
{
  int d = blockIdx.x * 4 + (threadIdx.x >> 6);
  if (d >= NN) return;
  int c = (threadIdx.x & 63) * 2;
  float v0 = b[c]     + b[128 + c]     + b[256 + c];
  float v1 = b[c + 1] + b[128 + c + 1] + b[256 + c + 1];
#pragma unroll
  for (int r = 0; r < 3; ++r) {
    int base = r * NN + d;
    int j0 = off[base], j1 = off[base + 1];
    float p0 = 0.f, p1 = 0.f;
    for (int j = j0; j < j1; ++j) {
      int s = srt[j];
      unsigned u = *(const unsigned*)&Y[(size_t)s * 384 + r * 128 + c];
      p0 += b2f((u16)(u & 0xFFFFu));
      p1 += b2f((u16)(u >> 16));
    }
    float sc = sin_[base];
    v0 += p0 * sc;
    v1 += p1 * sc;
  }
  *(float2*)&acc[(size_t)d * 128 + c] = make_float2(v0, v1);
}

// ---------------- FC (128x128) + bias + ReLU ----------------
static __global__ __launch_bounds__(256)
void k_fc_relu(const float* __restrict__ X, int M,
               const float* __restrict__ Wfc, const float* __restrict__ bfc,
               float* __restrict__ Z)
{
  __shared__ float Ws[128 * 64];
  __shared__ float xs[4][128];
  const int j0 = blockIdx.y * 64;
  const int t = threadIdx.x;

  for (int i = t; i < 128 * 64; i += 256) {
    int k = i >> 6, c = i & 63;
    Ws[i] = Wfc[k * 128 + j0 + c];
  }
  const int rl = t >> 6;
  const int c  = t & 63;
  const float bb = bfc[j0 + c];
  __syncthreads();

  for (int row0 = blockIdx.x * 4; row0 < M; row0 += gridDim.x * 4) {
    int row = row0 + rl;
    if (row < M) {
      xs[rl][c]      = X[(size_t)row * 128 + c];
      xs[rl][c + 64] = X[(size_t)row * 128 + c + 64];
    }
    __syncthreads();
    if (row < M) {
      float acc = bb;
#pragma unroll
      for (int k = 0; k < 128; ++k)
        acc = fmaf(xs[rl][k], Ws[k * 64 + c], acc);
      Z[(size_t)row * 128 + j0 + c] = fmaxf(acc, 0.f);
    }
    __syncthreads();
  }
}

// ---------------- BatchNorm ----------------
static __global__ void k_bn_stats(const float* __restrict__ Z, int M, float* __restrict__ stats) {
  int col = threadIdx.x;  // 128
  float s = 0.f, s2 = 0.f;
  for (int row = blockIdx.x; row < M; row += gridDim.x) {
    float v = Z[(size_t)row * 128 + col];
    s += v;
    s2 += v * v;
  }
  atomicAdd(&stats[col], s);
  atomicAdd(&stats[128 + col], s2);
}

static __global__ void k_bn_finalize(const float* __restrict__ stats, int M,
                                     const float* __restrict__ g, const float* __restrict__ beta,
                                     float* __restrict__ ab) {
  int j = threadIdx.x;  // 128
  float m  = stats[j] / (float)M;
  float v  = stats[128 + j] / (float)M - m * m;
  float inv = rsqrtf(v + EPSV) * g[j];
  ab[j]       = inv;
  ab[128 + j] = beta[j] - m * inv;
}

template<bool OUT_BF16>
static __global__ void k_bn_apply(const float* __restrict__ Z, const float* __restrict__ ab,
                                  void* __restrict__ out, int n) {
  int i = blockIdx.x * blockDim.x + threadIdx.x;
  if (i < n) {
    int j = i & 127;
    float v = Z[i] * ab[j] + ab[128 + j];
    if constexpr (OUT_BF16) ((u16*)out)[i] = f2b(v);
    else                    ((float*)out)[i] = v;
  }
}

// ---------------- host-side layer driver ----------------

template<int K, bool ABF16, bool OUT_BF16>
static void run_layer(const void* X,
                      const u16* Wt, const float* b,
                      const float* fcW, const float* fcb,
                      const float* g, const float* beta,
                      const int* off, const int* srt,
                      float* sOut, float* sIn, u16* Y, float* Z, float* acc,
                      float* stats, float* ab, void* out, hipStream_t stream)
{
  const int NT = (NN + 127) / 128;
  const int nblk = 24 * ((NT + 7) / 8);   // 8 XCD slots x 3 rels x ceil(NT/8)
  k_gemm_mfma<K, ABF16><<<nblk, 256, 0, stream>>>(X, Wt, sOut, Y, NN, NT);

  k_gather<<<(NN + 3) / 4, 256, 0, stream>>>(off, srt, sIn, Y, b, acc);

  k_fc_relu<<<dim3(2048, 2), 256, 0, stream>>>(acc, NN, fcW, fcb, Z);

  k_zero<<<1, 256, 0, stream>>>(stats, 256);
  k_bn_stats<<<1024, 128, 0, stream>>>(Z, NN, stats);
  k_bn_finalize<<<1, 128, 0, stream>>>(stats, NN, g, beta, ab);
  k_bn_apply<OUT_BF16><<<(NN * HID + 255) / 256, 256, 0, stream>>>(Z, ab, out, NN * HID);
}

extern "C" void kernel_launch(void* const* d_in, const int* in_sizes, int n_in,
                              void* d_out, int out_size, void* d_ws, size_t ws_size,
                              hipStream_t stream)
{
  const float* x    = (const float*)d_in[0];
  const int*   seq  = (const int*)d_in[1];
  const int*   knn  = (const int*)d_in[2];
  const int*   dis  = (const int*)d_in[3];
  const float* W0   = (const float*)d_in[4];
  const float* b0   = (const float*)d_in[5];
  const float* fcW0 = (const float*)d_in[6];
  const float* fcb0 = (const float*)d_in[7];
  const float* g0   = (const float*)d_in[8];
  const float* be0  = (const float*)d_in[9];
  const float* W1   = (const float*)d_in[10];
  const float* b1   = (const float*)d_in[11];
  const float* fcW1 = (const float*)d_in[12];
  const float* fcb1 = (const float*)d_in[13];
  const float* g1   = (const float*)d_in[14];
  const float* be1  = (const float*)d_in[15];

  const int E[3] = { in_sizes[1] / 2, in_sizes[2] / 2, in_sizes[3] / 2 };
  const int* srcs[3] = { seq, knn, dis };

  const size_t N = NN;
  const int M3 = 3 * NN;

  float* ws    = (float*)d_ws;
  float* sOut  = ws;                        // 3N
  float* sIn   = sOut + 3 * N;              // 3N
  float* acc   = sIn + 3 * N;               // N*128
  float* stats = acc + N * 128;             // 256
  float* ab    = stats + 256;               // 256
  u16*   Y     = (u16*)(ab + 256);          // N*384 bf16 (Z aliases: Y dead after gather)
  float* Z     = (float*)Y;                 // N*128 f32
  u16*   h16   = Y + N * 384;               // N*128 bf16
  u16*   Wt0   = h16 + N * 128;             // 3*128*1280
  u16*   Wt1   = Wt0 + 3 * 128 * 1280;      // 3*128*128
  int*   counts= (int*)(Wt1 + 3 * 128 * 128);
  int*   off   = counts + (M3 + 1);
  int*   aux   = off + (M3 + 1);
  int*   cur   = aux + 1536;
  int*   srt   = cur + M3;                  // ETOT ints

  // weight transpose+convert
  k_cvt_w<<<(3 * 1280 * 128 + 255) / 256, 256, 0, stream>>>(W0, Wt0, 1280);
  k_cvt_w<<<(3 * 128 * 128 + 255) / 256, 256, 0, stream>>>(W1, Wt1, 128);

  // degrees
  k_zero<<<(6 * NN + 255) / 256, 256, 0, stream>>>(sOut, 6 * NN);
  for (int r = 0; r < 3; ++r) {
    k_deg<<<(E[r] + 255) / 256, 256, 0, stream>>>(
        srcs[r], srcs[r] + E[r], E[r], sOut + (size_t)r * N, sIn + (size_t)r * N);
  }
  k_counts<<<(M3 + 1 + 255) / 256, 256, 0, stream>>>(sIn, counts, M3);
  k_rsqrt_clip<<<(6 * NN + 255) / 256, 256, 0, stream>>>(sOut, 6 * NN);

  // CSR: exclusive scan of counts[M3+1] -> off
  const int nsc = M3 + 1;
  const int nb  = (nsc + 255) / 256;
  k_scan1<<<nb, 256, 0, stream>>>(counts, off, aux, nsc);
  k_scan2<<<1, 256, 0, stream>>>(aux, nb);
  k_scan3<<<nb, 256, 0, stream>>>(off, aux, nsc);

  k_zero_i<<<(M3 + 255) / 256, 256, 0, stream>>>(cur, M3);
  for (int r = 0; r < 3; ++r) {
    k_fill<<<(E[r] + 255) / 256, 256, 0, stream>>>(
        srcs[r], srcs[r] + E[r], E[r], off, cur, r * NN, srt);
  }

  // layer 0: x f32 [N,1280] -> h16 bf16 [N,128]
  run_layer<1280, false, true>(x, Wt0, b0, fcW0, fcb0, g0, be0, off, srt,
                               sOut, sIn, Y, Z, acc, stats, ab, h16, stream);

  // layer 1: h16 bf16 [N,128] -> d_out f32 [N,128]
  run_layer<128, true, false>(h16, Wt1, b1, fcW1, fcb1, g1, be1, off, srt,
                              sOut, sIn, Y, Z, acc, stats, ab, d_out, stream);
}